// Round 5
// baseline (231.200 us; speedup 1.0000x reference)
//
#include <hip/hip_runtime.h>

// FourierFFTLayer: ifft(fft(x, axis=-1)).real on real float32 == identity
// (FFT round-trip absmax ~1.6e-2 vs 1.08e-1 threshold).
//
// Evidence ledger (headline = ~160us harness poison fills + our copy):
//  R0: 1-f4/thread one-shot, 32768 blk, plain      copy ~59us (219.0) best
//  R1: batch-8 stride-16MB, NT both                copy ~70us (230.7)
//  R2: batch-8 stride-16MB, plain                  copy ~82us (241.6)
//      FETCH=64MB (half input LLC-hit), WRITE=131MB, 2.2 TB/s HBM-visible
//  R3: batch-8 chunked-32KB, plain                 copy ~67us (227.5)
//  R4: R0 + NT stores                              copy ~61us (220.9)
//  Conclusions: batching hurts, NT neutral. Best = 4.5 TB/s effective
//  copy vs 6.29 TB/s documented float4-copy ceiling (m13) => ~16us
//  headroom IF the ceiling is reachable here.
//
// R5: the one untried documented config -- G11 grid-stride with 8
// blocks/CU (2048 blocks), persistent waves, 16 iterations/thread.
// vs R0 one-shot: no 32768-block dispatch/retire stream, and iterations
// pipeline (iter i+1's load issues while iter i's store is in flight;
// no inter-iteration dependency). Temporal window stays compact: all
// resident waves sweep one ~8MB contiguous slice per round.
// If this doesn't move, 4.5 TB/s is the environment's copy ceiling and
// the kernel is at roofline (fills = 73% of headline, untouchable).

typedef float f32x4 __attribute__((ext_vector_type(4)));

__global__ __launch_bounds__(256) void identity_copy_gs(
        const f32x4* __restrict__ in, f32x4* __restrict__ out, int n4) {
    int i = blockIdx.x * blockDim.x + threadIdx.x;
    const int stride = gridDim.x * blockDim.x;   // 524288 f4 = 8 MB window
    for (; i < n4; i += stride) {
        out[i] = in[i];
    }
}

extern "C" void kernel_launch(void* const* d_in, const int* in_sizes, int n_in,
                              void* d_out, int out_size, void* d_ws, size_t ws_size,
                              hipStream_t stream) {
    (void)in_sizes; (void)n_in; (void)d_ws; (void)ws_size;
    const f32x4* x = (const f32x4*)d_in[0];
    f32x4* out = (f32x4*)d_out;
    int n4 = out_size / 4;  // 8388608 float4s

    const int block = 256;
    const int grid = 2048;  // 8 blocks/CU x 256 CUs; 16 iters/thread
    identity_copy_gs<<<grid, block, 0, stream>>>(x, out, n4);
}

// Round 6
// 219.221 us; speedup vs baseline: 1.0546x; 1.0546x over previous
//
#include <hip/hip_runtime.h>

// FourierFFTLayer: ifft(fft(x, axis=-1)).real on real float32 == identity
// (FFT round-trip absmax ~1.6e-2 vs 1.08e-1 threshold). Kernel = D2D copy.
//
// FINAL: restore the proven-best configuration (R0, 219.0 us headline).
//
// Evidence ledger (headline = ~160us harness poison fills + our copy):
//  R0: 1-f4/thread one-shot, 32768 blk, plain   copy ~59us (219.0)  BEST
//  R4: R0 + NT stores                           copy ~61us (220.9)
//  R3: batch-8 chunked-32KB, plain              copy ~67us (227.5)
//  R1: batch-8 stride-16MB, NT both             copy ~70us (230.7)
//  R5: grid-stride, 2048 blk persistent         copy ~71us (231.2)
//  R2: batch-8 stride-16MB, plain               copy ~82us (241.6)
//
// Conclusions from 6 structural variants:
//  - Per-thread batching (any arrangement) and persistent grid-stride all
//    LOSE to the one-shot sweep where the block dispatcher provides the
//    sequential address stream. NT hints are neutral-to-harmful.
//  - rocprof (R2): FETCH=64MB (half the input LLC-resident despite 1GB/iter
//    poison sweep), WRITE=131MB, zero bank conflicts, VALUBusy ~1%.
//  - Copy runs at ~4.5 TB/s effective vs 6.3 TB/s clean-environment copy
//    ceiling; the gap is poisoned-LLC state + fill writeback drain
//    (harness-controlled), not kernel structure -- 5/5 targeted attempts
//    to close it failed.
//  - Harness fills: 2 x ~80us @ 84% HBM peak = 73% of headline, untouchable.

typedef float f32x4 __attribute__((ext_vector_type(4)));

__global__ __launch_bounds__(256) void identity_copy_f4(
        const f32x4* __restrict__ in, f32x4* __restrict__ out, int n4) {
    int i = blockIdx.x * blockDim.x + threadIdx.x;
    int stride = gridDim.x * blockDim.x;
    for (; i < n4; i += stride) {
        out[i] = in[i];
    }
}

extern "C" void kernel_launch(void* const* d_in, const int* in_sizes, int n_in,
                              void* d_out, int out_size, void* d_ws, size_t ws_size,
                              hipStream_t stream) {
    (void)in_sizes; (void)n_in; (void)d_ws; (void)ws_size;
    const f32x4* x = (const f32x4*)d_in[0];
    f32x4* out = (f32x4*)d_out;
    int n4 = out_size / 4;  // 33554432 floats / 4 = 8388608 float4s
    const int block = 256;
    int grid = (n4 + block - 1) / block;  // 32768 blocks, one float4/thread
    identity_copy_f4<<<grid, block, 0, stream>>>(x, out, n4);
}